// Round 7
// baseline (328.885 us; speedup 1.0000x reference)
//
#include <hip/hip_runtime.h>
#include <math.h>

#define NN 100000
#define NE 1600000
#define CH 128
#define OUTC 16
#define NG 64

#define CBSH 9                      // 512 nodes per coarse bucket
#define NCB 196                     // ceil(NN / 512)
#define CHK 8192                    // edges per passA block
#define CAP 10240                   // fixed bucket capacity (avg 8163, sd~90 -> 20+ sigma margin)
#define MAXB 12288                  // csr staging capacity per bucket in passB

typedef __attribute__((ext_vector_type(8))) short bf16x8;
typedef __attribute__((ext_vector_type(4))) float f32x4;

__device__ __forceinline__ unsigned short f2bf(float f) {
    union { float f; unsigned u; } v; v.f = f;
    unsigned r = v.u + 0x7FFF + ((v.u >> 16) & 1);   // RNE
    return (unsigned short)(r >> 16);
}
__device__ __forceinline__ float bflo(unsigned u) {
    union { unsigned u; float f; } v; v.u = u << 16; return v.f;
}
__device__ __forceinline__ float bfhi(unsigned u) {
    union { unsigned u; float f; } v; v.u = u & 0xffff0000u; return v.f;
}

// ---------------- prep: cast W1/W2 -> WT bf16, zero gfill/pooled, build gptr ----------------
__global__ void k_prep(const float* __restrict__ W1, const float* __restrict__ W2,
                       unsigned short* __restrict__ wt1, unsigned short* __restrict__ wt2,
                       const int* __restrict__ batch, int* __restrict__ gptr,
                       int* __restrict__ gfill, float* __restrict__ pooled) {
    int i = blockIdx.x * 256 + threadIdx.x;
    if (i < CH * CH) {
        int k = i >> 7, n = i & 127;
        wt1[n * CH + k] = f2bf(W1[i]);
    } else if (i < 2 * CH * CH) {
        int j = i - CH * CH;
        int k = j >> 7, n = j & 127;
        wt2[n * CH + k] = f2bf(W2[j]);
    }
    if (i < NCB) gfill[i] = 0;
    if (i < NG * CH) pooled[i] = 0.f;
    if (i < NN) {
        int b = batch[i];
        int prev = (i == 0) ? -1 : batch[i - 1];
        for (int g = prev + 1; g <= b; g++) gptr[g] = i;
        if (i == NN - 1) {
            for (int g = b + 1; g <= NG; g++) gptr[g] = NN;
        }
    }
}

// ---------------- pass A: counting-sort edges into fixed-capacity coarse buckets ----------------
__global__ __launch_bounds__(1024) void k_passA(const int* __restrict__ src, const int* __restrict__ dst,
                        int* __restrict__ gfill, unsigned* __restrict__ ebuf) {
    __shared__ unsigned lbuf[CHK];
    __shared__ unsigned char lbyte[CHK];
    __shared__ int hcnt[NCB];
    __shared__ int hbase[256];   // inclusive scan of hcnt
    __shared__ int goff[NCB];
    int t = threadIdx.x;
    if (t < NCB) hcnt[t] = 0;
    __syncthreads();
    int base = blockIdx.x * CHK;
    int cb[8], slot[8]; unsigned pk[8];
#pragma unroll
    for (int i = 0; i < 8; i++) {
        int e = base + i * 1024 + t;
        cb[i] = -1;
        if (e < NE) {
            int d = dst[e], s = src[e];
            cb[i] = d >> CBSH;
            pk[i] = ((unsigned)s << CBSH) | (unsigned)(d & 511);
            slot[i] = atomicAdd(&hcnt[cb[i]], 1);
        }
    }
    __syncthreads();
    if (t < 256) hbase[t] = (t < NCB) ? hcnt[t] : 0;
    __syncthreads();
    for (int off = 1; off < 256; off <<= 1) {
        int v = 0;
        if (t < 256 && t >= off) v = hbase[t - off];
        __syncthreads();
        if (t < 256) hbase[t] += v;
        __syncthreads();
    }
    if (t < NCB) {
        int c = hcnt[t];
        int g = c ? atomicAdd(&gfill[t], c) : 0;
        goff[t] = t * CAP + g - (hbase[t] - c);
    }
    __syncthreads();
#pragma unroll
    for (int i = 0; i < 8; i++) {
        if (cb[i] >= 0) {
            int pos = hbase[cb[i]] - hcnt[cb[i]] + slot[i];
            lbuf[pos] = pk[i];
            lbyte[pos] = (unsigned char)cb[i];
        }
    }
    __syncthreads();
    int total = min(NE - base, CHK);
    for (int p = t; p < total; p += 1024) {
        unsigned v = lbuf[p];
        int b = lbyte[p];
        ebuf[goff[b] + p] = v;
    }
}

// ---------------- pass B: per-bucket node sort -> csr/degi/rowst/dis ----------------
__global__ __launch_bounds__(1024) void k_passB(const unsigned* __restrict__ ebuf, const int* __restrict__ gfill,
                        int* __restrict__ degi, int* __restrict__ rowst,
                        float* __restrict__ dis, int* __restrict__ csr) {
    __shared__ int cnt[512];
    __shared__ int nbase[512];
    __shared__ int fill[512];
    __shared__ int stage[MAXB];
    int t = threadIdx.x;
    int cb = blockIdx.x;
    int nb0 = cb << CBSH;
    int ncnt = min(512, NN - nb0);
    int e0 = cb * CAP;
    int e1 = e0 + gfill[cb];
    if (t < 512) { cnt[t] = 0; fill[t] = 0; }
    __syncthreads();
    for (int e = e0 + t; e < e1; e += 1024)
        atomicAdd(&cnt[ebuf[e] & 511], 1);
    __syncthreads();
    if (t < 512) nbase[t] = cnt[t];
    __syncthreads();
    for (int off = 1; off < 512; off <<= 1) {
        int v = 0;
        if (t < 512 && t >= off) v = nbase[t - off];
        __syncthreads();
        if (t < 512) nbase[t] += v;
        __syncthreads();
    }
    for (int e = e0 + t; e < e1; e += 1024) {
        unsigned v = ebuf[e];
        int local = v & 511;
        int s = atomicAdd(&fill[local], 1);
        stage[nbase[local] - cnt[local] + s] = (int)(v >> CBSH);
    }
    __syncthreads();
    int total = e1 - e0;
    for (int p = t; p < total; p += 1024) csr[e0 + p] = stage[p];
    if (t < ncnt) {
        int c = cnt[t];
        degi[nb0 + t] = c;
        rowst[nb0 + t] = e0 + nbase[t] - c;   // absolute index into padded csr
        dis[nb0 + t] = rsqrtf((float)c + 1.0f);
    }
}

// ---------------- MFMA GEMM: out[row] = bf16( (A[row] @ W) * dis[row] ) ----------------
template<bool F32IN>
__launch_bounds__(256, 2)
__global__ void k_gemm(const void* __restrict__ Av,
                       const unsigned short* __restrict__ WT,
                       const float* __restrict__ dis,
                       unsigned short* __restrict__ out) {
    int tid = threadIdx.x;
    int wave = tid >> 6, lane = tid & 63;
    int quad = lane >> 4, l16 = lane & 15;

    int rbase = blockIdx.x * 128 + wave * 32;

    bf16x8 af[2][4];
#pragma unroll
    for (int s = 0; s < 2; s++) {
        int row = rbase + s * 16 + l16;
        if (row >= NN) row = NN - 1;
        if (F32IN) {
            const float* arow = (const float*)Av + (size_t)row * CH + quad * 8;
#pragma unroll
            for (int ks = 0; ks < 4; ks++) {
                float4 lo = *(const float4*)(arow + ks * 32);
                float4 hi = *(const float4*)(arow + ks * 32 + 4);
                union { bf16x8 v; unsigned short u[8]; } tmp;
                tmp.u[0] = f2bf(lo.x); tmp.u[1] = f2bf(lo.y);
                tmp.u[2] = f2bf(lo.z); tmp.u[3] = f2bf(lo.w);
                tmp.u[4] = f2bf(hi.x); tmp.u[5] = f2bf(hi.y);
                tmp.u[6] = f2bf(hi.z); tmp.u[7] = f2bf(hi.w);
                af[s][ks] = tmp.v;
            }
        } else {
            const unsigned short* arow = (const unsigned short*)Av + (size_t)row * CH + quad * 8;
#pragma unroll
            for (int ks = 0; ks < 4; ks++) af[s][ks] = *(const bf16x8*)(arow + ks * 32);
        }
    }

    f32x4 acc[2][8];
#pragma unroll
    for (int s = 0; s < 2; s++)
#pragma unroll
        for (int t = 0; t < 8; t++) acc[s][t] = (f32x4){0.f, 0.f, 0.f, 0.f};

#pragma unroll
    for (int t = 0; t < 8; t++) {
        const unsigned short* wcol = WT + (size_t)(t * 16 + l16) * CH + quad * 8;
        bf16x8 b0 = *(const bf16x8*)(wcol);
        bf16x8 b1 = *(const bf16x8*)(wcol + 32);
        bf16x8 b2 = *(const bf16x8*)(wcol + 64);
        bf16x8 b3 = *(const bf16x8*)(wcol + 96);
#pragma unroll
        for (int s = 0; s < 2; s++) {
            acc[s][t] = __builtin_amdgcn_mfma_f32_16x16x32_bf16(af[s][0], b0, acc[s][t], 0, 0, 0);
            acc[s][t] = __builtin_amdgcn_mfma_f32_16x16x32_bf16(af[s][1], b1, acc[s][t], 0, 0, 0);
            acc[s][t] = __builtin_amdgcn_mfma_f32_16x16x32_bf16(af[s][2], b2, acc[s][t], 0, 0, 0);
            acc[s][t] = __builtin_amdgcn_mfma_f32_16x16x32_bf16(af[s][3], b3, acc[s][t], 0, 0, 0);
        }
    }

#pragma unroll
    for (int s = 0; s < 2; s++) {
#pragma unroll
        for (int r = 0; r < 4; r++) {
            int orow = rbase + s * 16 + quad * 4 + r;
            if (orow < NN) {
                float d = dis[orow];
#pragma unroll
                for (int t = 0; t < 8; t++) {
                    out[(size_t)orow * CH + t * 16 + l16] = f2bf(acc[s][t][r] * d);
                }
            }
        }
    }
}

// ---------------- layer-1 aggregation: out = bf16(relu(dis*(gather+self) + b)) ----------------
__global__ void k_agg(const unsigned short* __restrict__ ht, const int* __restrict__ rowst,
                      const int* __restrict__ degi, const int* __restrict__ csr,
                      const float* __restrict__ dis, const float* __restrict__ bias,
                      unsigned short* __restrict__ out) {
    int wave = threadIdx.x >> 6;
    int lane = threadIdx.x & 63;
    int n = blockIdx.x * 4 + wave;
    if (n >= NN) return;
    const unsigned* base = (const unsigned*)ht;
    unsigned sv = base[(size_t)n * 64 + lane];
    float a0[8], a1[8];
    a0[0] = bflo(sv); a1[0] = bfhi(sv);
#pragma unroll
    for (int u = 1; u < 8; u++) { a0[u] = 0.f; a1[u] = 0.f; }
    int start = __builtin_amdgcn_readfirstlane(rowst[n]);
    int c = __builtin_amdgcn_readfirstlane(degi[n]);
    int j = 0;
    for (; j + 7 < c; j += 8) {
        int idx[8];
#pragma unroll
        for (int u = 0; u < 8; u++) idx[u] = csr[start + j + u];
        unsigned v[8];
#pragma unroll
        for (int u = 0; u < 8; u++) v[u] = base[(size_t)idx[u] * 64 + lane];
#pragma unroll
        for (int u = 0; u < 8; u++) { a0[u] += bflo(v[u]); a1[u] += bfhi(v[u]); }
    }
    for (; j < c; j++) {
        unsigned v0 = base[(size_t)csr[start + j] * 64 + lane];
        a0[j & 7] += bflo(v0); a1[j & 7] += bfhi(v0);
    }
#pragma unroll
    for (int off = 4; off >= 1; off >>= 1)
#pragma unroll
        for (int u = 0; u < off; u++) { a0[u] += a0[u + off]; a1[u] += a1[u + off]; }
    float d = dis[n];
    float bb0 = bias[lane * 2], bb1 = bias[lane * 2 + 1];
    float ox = fmaxf(fmaf(d, a0[0], bb0), 0.f);
    float oy = fmaxf(fmaf(d, a1[0], bb1), 0.f);
    unsigned pk = ((unsigned)f2bf(oy) << 16) | (unsigned)f2bf(ox);
    ((unsigned*)out)[(size_t)n * 64 + lane] = pk;
}

// ---------------- fused layer-2 aggregation + mean-pool partial sums ----------------
// 16 waves = 16 nodes per block; h2 is never materialized.
__global__ __launch_bounds__(1024) void k_aggpool(const unsigned short* __restrict__ ht,
                        const int* __restrict__ rowst, const int* __restrict__ degi,
                        const int* __restrict__ csr, const float* __restrict__ dis,
                        const float* __restrict__ bias, const int* __restrict__ batch,
                        float* __restrict__ pooled) {
    int wave = threadIdx.x >> 6;
    int lane = threadIdx.x & 63;
    int n = blockIdx.x * 16 + wave;          // grid sized so n < NN always
    const unsigned* base = (const unsigned*)ht;
    unsigned sv = base[(size_t)n * 64 + lane];
    float a0[8], a1[8];
    a0[0] = bflo(sv); a1[0] = bfhi(sv);
#pragma unroll
    for (int u = 1; u < 8; u++) { a0[u] = 0.f; a1[u] = 0.f; }
    int start = __builtin_amdgcn_readfirstlane(rowst[n]);
    int c = __builtin_amdgcn_readfirstlane(degi[n]);
    int j = 0;
    for (; j + 7 < c; j += 8) {
        int idx[8];
#pragma unroll
        for (int u = 0; u < 8; u++) idx[u] = csr[start + j + u];
        unsigned v[8];
#pragma unroll
        for (int u = 0; u < 8; u++) v[u] = base[(size_t)idx[u] * 64 + lane];
#pragma unroll
        for (int u = 0; u < 8; u++) { a0[u] += bflo(v[u]); a1[u] += bfhi(v[u]); }
    }
    for (; j < c; j++) {
        unsigned v0 = base[(size_t)csr[start + j] * 64 + lane];
        a0[j & 7] += bflo(v0); a1[j & 7] += bfhi(v0);
    }
#pragma unroll
    for (int off = 4; off >= 1; off >>= 1)
#pragma unroll
        for (int u = 0; u < off; u++) { a0[u] += a0[u + off]; a1[u] += a1[u + off]; }
    float d = dis[n];
    float bb0 = bias[lane * 2], bb1 = bias[lane * 2 + 1];
    float ox = fmaxf(fmaf(d, a0[0], bb0), 0.f);
    float oy = fmaxf(fmaf(d, a1[0], bb1), 0.f);

    // pool: bf16-quantize first to match reference dtype path of prior rounds
    ox = bflo((unsigned)f2bf(ox));
    oy = bflo((unsigned)f2bf(oy));

    int g = batch[n];
    int g0 = batch[blockIdx.x * 16];
    int g15 = batch[blockIdx.x * 16 + 15];
    if (g0 == g15) {                     // block entirely in one graph (common case)
        __shared__ float sred[2][16][64];
        sred[0][wave][lane] = ox; sred[1][wave][lane] = oy;
        __syncthreads();
#pragma unroll
        for (int off = 8; off >= 1; off >>= 1) {
            if (wave < off) {
                sred[0][wave][lane] += sred[0][wave + off][lane];
                sred[1][wave][lane] += sred[1][wave + off][lane];
            }
            __syncthreads();
        }
        if (wave == 0) {
            atomicAdd(&pooled[g0 * CH + lane * 2],     sred[0][0][lane]);
            atomicAdd(&pooled[g0 * CH + lane * 2 + 1], sred[1][0][lane]);
        }
    } else {                             // graph boundary block (rare): per-node atomics
        atomicAdd(&pooled[g * CH + lane * 2],     ox);
        atomicAdd(&pooled[g * CH + lane * 2 + 1], oy);
    }
}

// ---------------- final FC: out = (pooled/cnt) @ Wfc + bfc ----------------
__global__ void k_final(const float* __restrict__ pooled, const int* __restrict__ gptr,
                        const float* __restrict__ Wfc, const float* __restrict__ bfc,
                        float* __restrict__ out) {
    int idx = blockIdx.x * 256 + threadIdx.x;
    if (idx >= NG * OUTC) return;
    int g = idx >> 4, o = idx & 15;
    float c = (float)(gptr[g + 1] - gptr[g]);
    float inv = 1.0f / fmaxf(c, 1.0f);
    float s = 0.f;
    for (int k = 0; k < CH; k++) s += pooled[g * CH + k] * Wfc[k * OUTC + o];
    out[idx] = fmaf(s, inv, bfc[o]);
}

extern "C" void kernel_launch(void* const* d_in, const int* in_sizes, int n_in,
                              void* d_out, int out_size, void* d_ws, size_t ws_size,
                              hipStream_t stream) {
    (void)in_sizes; (void)n_in; (void)out_size; (void)ws_size;
    const float* x   = (const float*)d_in[0];
    const float* W1  = (const float*)d_in[1];
    const float* b1  = (const float*)d_in[2];
    const float* W2  = (const float*)d_in[3];
    const float* b2  = (const float*)d_in[4];
    const float* Wfc = (const float*)d_in[5];
    const float* bfc = (const float*)d_in[6];
    const int* ei    = (const int*)d_in[7];
    const int* batch = (const int*)d_in[8];
    const int* esrc = ei;
    const int* edst = ei + NE;
    float* out = (float*)d_out;

    char* w = (char*)d_ws;
    unsigned short* bufA = (unsigned short*)w; w += (size_t)NN * CH * 2;
    unsigned short* bufB = (unsigned short*)w; w += (size_t)NN * CH * 2;
    unsigned short* wt1  = (unsigned short*)w; w += (size_t)CH * CH * 2;
    unsigned short* wt2  = (unsigned short*)w; w += (size_t)CH * CH * 2;
    unsigned* ebuf = (unsigned*)w; w += (size_t)NCB * CAP * 4;
    int* csr    = (int*)w;    w += (size_t)NCB * CAP * 4;
    int* degi   = (int*)w;    w += (size_t)NN * 4;
    int* rowst  = (int*)w;    w += (size_t)NN * 4;
    float* dis  = (float*)w;  w += (size_t)NN * 4;
    int* gfill  = (int*)w;    w += NCB * 4;
    int* gptr   = (int*)w;    w += (NG + 1) * 4;
    float* pooled = (float*)w; w += (size_t)NG * CH * 4;

    const int sortBlocks = (NE + CHK - 1) / CHK;   // 196
    const int gemmBlocks = (NN + 127) / 128;       // 782

    k_prep<<<(NN + 255) / 256, 256, 0, stream>>>(W1, W2, wt1, wt2, batch, gptr, gfill, pooled);
    k_passA<<<sortBlocks, 1024, 0, stream>>>(esrc, edst, gfill, ebuf);
    k_passB<<<NCB, 1024, 0, stream>>>(ebuf, gfill, degi, rowst, dis, csr);

    // layer 1 (fp32 input, fused cast)
    k_gemm<true><<<gemmBlocks, 256, 0, stream>>>(x, wt1, dis, bufA);
    k_agg<<<NN / 4, 256, 0, stream>>>(bufA, rowst, degi, csr, dis, b1, bufB);
    // layer 2 (bf16 input)
    k_gemm<false><<<gemmBlocks, 256, 0, stream>>>(bufB, wt2, dis, bufA);
    // fused layer-2 aggregation + pooling (h2 never materialized)
    k_aggpool<<<NN / 16, 1024, 0, stream>>>(bufA, rowst, degi, csr, dis, b2, batch, pooled);

    k_final<<<(NG * OUTC + 255) / 256, 256, 0, stream>>>(pooled, gptr, Wfc, bfc, out);
}